// Round 7
// baseline (446.684 us; speedup 1.0000x reference)
//
#include <hip/hip_runtime.h>

#define GN 8192
#define IN_DIM 512
#define ODIM 64
#define SLOPE 0.2f
#define JSPLIT 16
#define JCH (GN / JSPLIT)      // 512 cols per tile
#define LSTRIDE 68             // LDS mask row stride bytes (17 words -> conflict-free)
#define NTILE 2                // tiles per persistent block

typedef __attribute__((ext_vector_type(4))) float  f32x4;
typedef __attribute__((ext_vector_type(4))) int    i32x4;
typedef __attribute__((ext_vector_type(8))) short  bf16x8;
typedef __attribute__((ext_vector_type(4))) unsigned short u16x4;

static __device__ __forceinline__ float bf2f(unsigned short u) {
    return __uint_as_float(((unsigned)u) << 16);
}
static __device__ __forceinline__ unsigned short f2bf(float f) {
    union { float f; unsigned u; } c; c.f = f;
    unsigned b = c.u;
    return (unsigned short)((b + 0x7fffu + ((b >> 16) & 1u)) >> 16);  // RNE
}

// load 8 contiguous elements as bf16x8, from either wire dtype
static __device__ __forceinline__ bf16x8 load8(const void* p, size_t off, int f32) {
    if (f32) {
        f32x4 lo = *(const f32x4*)((const float*)p + off);
        f32x4 hi = *(const f32x4*)((const float*)p + off + 4);
        bf16x8 r;
        #pragma unroll
        for (int q = 0; q < 4; ++q) {
            r[q]     = (short)f2bf(lo[q]);
            r[4 + q] = (short)f2bf(hi[q]);
        }
        return r;
    }
    return *(const bf16x8*)((const ushort*)p + off);
}

// Kernel 1 (MFMA GEMM): Wh = x@W^T. Epilogue writes WhTp in B-operand-native
// layout: 16B unit U(jblk,n) = WhTp[(jblk*64+n)*8 .. +8) = Wh[jblk*8+0..7][n].
// Also s, d (fp32), dmax (atomicMax), dflag.
extern "C" __global__ __launch_bounds__(256)
void gat_proj(const void* __restrict__ x_, const void* __restrict__ W_,
              const void* __restrict__ as_, const void* __restrict__ ad_,
              ushort* __restrict__ WhTp, float* __restrict__ s_arr,
              float* __restrict__ d_arr, int* __restrict__ dmax_bits,
              int* __restrict__ dflag)
{
    const int wave = threadIdx.x >> 6;
    const int lane = threadIdx.x & 63;
    unsigned xw = ((const unsigned*)x_)[lane];
    unsigned ef = (xw >> 23) & 0xffu;
    unsigned long long vt = __ballot(ef > 60u && ef < 180u);
    const int f32 = (__popcll(vt) >= 32) ? 1 : 0;
    if (blockIdx.x == 0 && threadIdx.x == 0) *dflag = f32;

    const int quad = lane >> 4;
    const int lq   = lane & 15;
    const int i0   = blockIdx.x * 64 + wave * 16;

    f32x4 acc[4] = {{0,0,0,0},{0,0,0,0},{0,0,0,0},{0,0,0,0}};
    const size_t arow = (size_t)(i0 + lq) * IN_DIM;
    #pragma unroll 2
    for (int k0 = 0; k0 < IN_DIM; k0 += 32) {
        const int kk = k0 + quad * 8;
        bf16x8 a  = load8(x_, arow + kk, f32);
        bf16x8 b0 = load8(W_, (size_t)( 0 + lq) * IN_DIM + kk, f32);
        bf16x8 b1 = load8(W_, (size_t)(16 + lq) * IN_DIM + kk, f32);
        bf16x8 b2 = load8(W_, (size_t)(32 + lq) * IN_DIM + kk, f32);
        bf16x8 b3 = load8(W_, (size_t)(48 + lq) * IN_DIM + kk, f32);
        acc[0] = __builtin_amdgcn_mfma_f32_16x16x32_bf16(a, b0, acc[0], 0, 0, 0);
        acc[1] = __builtin_amdgcn_mfma_f32_16x16x32_bf16(a, b1, acc[1], 0, 0, 0);
        acc[2] = __builtin_amdgcn_mfma_f32_16x16x32_bf16(a, b2, acc[2], 0, 0, 0);
        acc[3] = __builtin_amdgcn_mfma_f32_16x16x32_bf16(a, b3, acc[3], 0, 0, 0);
    }
    // lane holds Wh[i = i0+quad*4+r][n = t*16+lq] in acc[t][r]
    float av_s[4], av_d[4];
    #pragma unroll
    for (int t = 0; t < 4; ++t) {
        const int n = t * 16 + lq;
        av_s[t] = f32 ? ((const float*)as_)[n] : bf2f(((const ushort*)as_)[n]);
        av_d[t] = f32 ? ((const float*)ad_)[n] : bf2f(((const ushort*)ad_)[n]);
    }
    // WhTp write: rows i0+quad*4..+3 are halfwords (quad&1)*4..+3 of unit
    // jblk = (i0>>3)+(quad>>1): one aligned 8B store per t.
    #pragma unroll
    for (int t = 0; t < 4; ++t) {
        u16x4 pk;
        #pragma unroll
        for (int r = 0; r < 4; ++r) pk[r] = f2bf(acc[t][r]);
        const size_t hw = ((size_t)((i0 >> 3) + (quad >> 1)) * 64 + t * 16 + lq) * 8
                          + (quad & 1) * 4;
        *(u16x4*)(WhTp + hw) = pk;
    }
    float ps[4], pd[4];
    #pragma unroll
    for (int r = 0; r < 4; ++r) {
        float s = 0.f, d = 0.f;
        #pragma unroll
        for (int t = 0; t < 4; ++t) {
            s = fmaf(acc[t][r], av_s[t], s);
            d = fmaf(acc[t][r], av_d[t], d);
        }
        #pragma unroll
        for (int off = 1; off < 16; off <<= 1) {
            s += __shfl_xor(s, off);
            d += __shfl_xor(d, off);
        }
        ps[r] = s; pd[r] = d;
    }
    if (lq == 0) {
        float dmx = -1e30f;
        #pragma unroll
        for (int r = 0; r < 4; ++r) {
            s_arr[i0 + quad * 4 + r] = ps[r];
            d_arr[i0 + quad * 4 + r] = pd[r];
            dmx = fmaxf(dmx, pd[r]);
        }
        if (dmx > 0.f) atomicMax(dmax_bits, __float_as_int(dmx));
    }
}

// Kernel 2: persistent fused attention. 1024 blocks = 128 ib x 8 js0; block
// covers tiles js = js0, js0+8. adj staged via 3-deep register ring (pack lag
// 2) into double-buffered LDS masks; per-iter operand prefetch (distance 1)
// issued BEFORE the adj chunk so operand waits never drain adj loads
// (in-order vmcnt retirement). WhTp layout makes b-frag loads 4x256B
// contiguous and L1-shared across the block's 4 waves.
extern "C" __global__ __launch_bounds__(256, 4)
void gat_attn(const int* __restrict__ adj, const ushort* __restrict__ WhTp,
              const float* __restrict__ s_arr, const float* __restrict__ d_arr,
              const int* __restrict__ dmax_bits,
              float* __restrict__ accum, float* __restrict__ lsum)
{
    __shared__ unsigned char mb[2][64 * LSTRIDE];
    const int b    = blockIdx.x;        // 0..1023
    const int ib   = b & 127;
    const int js0  = b >> 7;            // 0..7
    const int wave = threadIdx.x >> 6;
    const int lane = threadIdx.x & 63;
    const int quad = lane >> 4;
    const int lq   = lane & 15;
    const int i0   = ib * 64;
    const int li   = wave * 16 + lq;
    const int i    = i0 + li;
    const float dmax = __int_as_float(*dmax_bits);
    const float si = s_arr[i];
    const float tbv = si + dmax;
    const float mi = fmaxf(tbv, SLOPE * tbv);   // row-logit upper bound

    const size_t adjbase = (size_t)i0 * GN + lane * 8;

    i32x4 ra[3], rb[3];
    auto pack = [&](const i32x4& va, const i32x4& vb, int c, int bufsel) {
        unsigned byte = 0;
        #pragma unroll
        for (int q = 0; q < 4; ++q) {
            byte |= (va[q] > 0 ? 1u : 0u) << q;
            byte |= (vb[q] > 0 ? 1u : 0u) << (4 + q);
        }
        mb[bufsel][(c * 4 + wave) * LSTRIDE + lane] = (unsigned char)byte;
    };

    f32x4 acc0 = {0,0,0,0}, acc1 = {0,0,0,0}, acc2 = {0,0,0,0}, acc3 = {0,0,0,0};
    f32x4 acc4 = {0,0,0,0};             // row-sum via ones-MFMA
    bf16x8 ones;
    #pragma unroll
    for (int q = 0; q < 8; ++q) ones[q] = (short)0x3F80;

    // ---- prologue: stage tile 0 -> mb[0] ----
    {
        const int jb = js0 * JCH;
        #pragma unroll
        for (int c = 0; c < 16; ++c) {
            const int* rp = adj + adjbase + (size_t)(c * 4 + wave) * GN + jb;
            ra[c % 3] = ((const i32x4*)rp)[0];
            rb[c % 3] = ((const i32x4*)rp)[1];
            if (c >= 2) pack(ra[(c - 2) % 3], rb[(c - 2) % 3], c - 2, 0);
        }
        pack(ra[14 % 3], rb[14 % 3], 14, 0);
        pack(ra[15 % 3], rb[15 % 3], 15, 0);
    }
    __syncthreads();

    // preload operands for tile 0, iter 0
    int jpre = js0 * JCH + quad * 8;
    f32x4 dv0 = *(const f32x4*)(d_arr + jpre);
    f32x4 dv1 = *(const f32x4*)(d_arr + jpre + 4);
    const ushort* bb0 = WhTp + ((size_t)((js0 * JCH) >> 3) + quad) * 512;  // *64 units *8 hw
    bf16x8 b0 = *(const bf16x8*)(bb0 + ( 0 + lq) * 8);
    bf16x8 b1 = *(const bf16x8*)(bb0 + (16 + lq) * 8);
    bf16x8 b2 = *(const bf16x8*)(bb0 + (32 + lq) * 8);
    bf16x8 b3 = *(const bf16x8*)(bb0 + (48 + lq) * 8);

    #pragma unroll 1
    for (int t = 0; t < NTILE; ++t) {
        const int jb   = (js0 + 8 * t) * JCH;
        const int jbn  = jb + 8 * JCH;
        const bool more = (t < NTILE - 1);
        const int buf  = t & 1, nbuf = buf ^ 1;

        #pragma unroll
        for (int it = 0; it < 16; ++it) {
            // 1) operand prefetch for next iter (issued before this iter's adj)
            const int jtb = (it < 15) ? jb : (more ? jbn : jb);
            const int itn = (it < 15) ? (it + 1) : 0;
            const int jn  = jtb + itn * 32 + quad * 8;
            f32x4 ndv0 = *(const f32x4*)(d_arr + jn);
            f32x4 ndv1 = *(const f32x4*)(d_arr + jn + 4);
            const ushort* nb = WhTp + ((size_t)(jtb >> 3) + itn * 4 + quad) * 512;
            bf16x8 nb0 = *(const bf16x8*)(nb + ( 0 + lq) * 8);
            bf16x8 nb1 = *(const bf16x8*)(nb + (16 + lq) * 8);
            bf16x8 nb2 = *(const bf16x8*)(nb + (32 + lq) * 8);
            bf16x8 nb3 = *(const bf16x8*)(nb + (48 + lq) * 8);
            // 2) issue next-tile adj chunk into the register ring
            if (more) {
                const int* rp = adj + adjbase + (size_t)(it * 4 + wave) * GN + jbn;
                ra[it % 3] = ((const i32x4*)rp)[0];
                rb[it % 3] = ((const i32x4*)rp)[1];
            }
            // 3) pack chunk it-2 (chunks it-1, it stay in flight)
            if (more && it >= 2)
                pack(ra[(it - 2) % 3], rb[(it - 2) % 3], it - 2, nbuf);
            // 4) compute iter it
            unsigned bw = *(const unsigned*)(&mb[buf][li * LSTRIDE + it * 4]);
            const unsigned m8 = (bw >> (quad * 8)) & 0xffu;
            float w[8];
            #pragma unroll
            for (int q = 0; q < 4; ++q) {
                float e0 = si + dv0[q];
                e0 = fmaxf(e0, SLOPE * e0);
                float v0 = __expf(e0 - mi);
                w[q] = ((m8 >> q) & 1u) ? v0 : 0.f;
                float e1 = si + dv1[q];
                e1 = fmaxf(e1, SLOPE * e1);
                float v1 = __expf(e1 - mi);
                w[4 + q] = ((m8 >> (4 + q)) & 1u) ? v1 : 0.f;
            }
            bf16x8 af;
            #pragma unroll
            for (int q = 0; q < 8; ++q) af[q] = (short)f2bf(w[q]);
            acc0 = __builtin_amdgcn_mfma_f32_16x16x32_bf16(af, b0, acc0, 0, 0, 0);
            acc1 = __builtin_amdgcn_mfma_f32_16x16x32_bf16(af, b1, acc1, 0, 0, 0);
            acc2 = __builtin_amdgcn_mfma_f32_16x16x32_bf16(af, b2, acc2, 0, 0, 0);
            acc3 = __builtin_amdgcn_mfma_f32_16x16x32_bf16(af, b3, acc3, 0, 0, 0);
            acc4 = __builtin_amdgcn_mfma_f32_16x16x32_bf16(af, ones, acc4, 0, 0, 0);
            dv0 = ndv0; dv1 = ndv1; b0 = nb0; b1 = nb1; b2 = nb2; b3 = nb3;
        }
        if (more) {
            pack(ra[14 % 3], rb[14 % 3], 14, nbuf);
            pack(ra[15 % 3], rb[15 % 3], 15, nbuf);
        }
        __syncthreads();
    }

    // epilogue: C/D col=lq, row=quad*4+r; acc4 holds row sums in every col
    const int orow = i0 + wave * 16 + quad * 4;
    if (lq == 0) {
        #pragma unroll
        for (int r = 0; r < 4; ++r) atomicAdd(&lsum[orow + r], acc4[r]);
    }
    #pragma unroll
    for (int r = 0; r < 4; ++r) {
        atomicAdd(&accum[(size_t)(orow + r) * ODIM +  0 + lq], acc0[r]);
        atomicAdd(&accum[(size_t)(orow + r) * ODIM + 16 + lq], acc1[r]);
        atomicAdd(&accum[(size_t)(orow + r) * ODIM + 32 + lq], acc2[r]);
        atomicAdd(&accum[(size_t)(orow + r) * ODIM + 48 + lq], acc3[r]);
    }
}

// Kernel 3: out = (accum / lsum), dtype per flag
extern "C" __global__ __launch_bounds__(256)
void gat_final(const float* __restrict__ accum, const float* __restrict__ lsum,
               const int* __restrict__ flag, void* __restrict__ out)
{
    const int idx = blockIdx.x * 256 + threadIdx.x;
    const float v = accum[idx] / lsum[idx >> 6];
    if (*flag) ((float*)out)[idx] = v;
    else       ((ushort*)out)[idx] = f2bf(v);
}

extern "C" void kernel_launch(void* const* d_in, const int* in_sizes, int n_in,
                              void* d_out, int out_size, void* d_ws, size_t ws_size,
                              hipStream_t stream)
{
    const void* x     = d_in[0];
    const int*  adj   = (const int*)d_in[1];
    const void* W     = d_in[2];
    const void* a_src = d_in[3];
    const void* a_dst = d_in[4];

    char* ws = (char*)d_ws;
    size_t off = 0;
    float* accum = (float*)(ws + off);  off += (size_t)GN * ODIM * 4;      // 2 MB
    float* lsum  = (float*)(ws + off);  off += (size_t)GN * 4;             // 32 KB
    int* dmax_bits = (int*)(ws + off);  off += 128;
    size_t zero_bytes = off;                                               // zero through dmax
    int* dflag = (int*)(ws + off);      off += 128;                        // written by gat_proj
    float* s_arr = (float*)(ws + off);  off += (size_t)GN * 4;
    float* d_arr = (float*)(ws + off);  off += (size_t)GN * 4;
    ushort* WhTp = (ushort*)(ws + off); off += (size_t)ODIM * GN * 2;      // 1 MB

    hipMemsetAsync(ws, 0, zero_bytes, stream);
    gat_proj<<<GN / 64, 256, 0, stream>>>(x, W, a_src, a_dst,
                                          WhTp, s_arr, d_arr, dmax_bits, dflag);
    gat_attn<<<1024, 256, 0, stream>>>(adj, WhTp, s_arr, d_arr,
                                       dmax_bits, accum, lsum);
    gat_final<<<GN * ODIM / 256, 256, 0, stream>>>(accum, lsum, dflag, d_out);
}